// Round 8
// baseline (380.612 us; speedup 1.0000x reference)
//
#include <hip/hip_runtime.h>
#include <hip/hip_bf16.h>

typedef __attribute__((ext_vector_type(8))) short bf16x8;
typedef __attribute__((ext_vector_type(4))) short bf16x4;
typedef __attribute__((ext_vector_type(4))) float floatx4;
typedef unsigned short u16;
typedef unsigned int u32;

#define DM 1024
#define SEQ 4096
#define NH 16
#define HD 64
#define CHUNK 128

__device__ __forceinline__ float bf2f(u16 x) {
    u32 u = ((u32)x) << 16;
    return __builtin_bit_cast(float, u);
}
__device__ __forceinline__ u16 f2bf(float f) {
    u32 u = __builtin_bit_cast(u32, f);
    u32 r = u + 0x7FFF + ((u >> 16) & 1);
    return (u16)(r >> 16);
}
__device__ __forceinline__ bf16x8 cvt8(const float* p) {
    floatx4 a = *(const floatx4*)p;
    floatx4 b = *(const floatx4*)(p + 4);
    bf16x8 r;
    r[0] = (short)f2bf(a[0]); r[1] = (short)f2bf(a[1]);
    r[2] = (short)f2bf(a[2]); r[3] = (short)f2bf(a[3]);
    r[4] = (short)f2bf(b[0]); r[5] = (short)f2bf(b[1]);
    r[6] = (short)f2bf(b[2]); r[7] = (short)f2bf(b[3]);
    return r;
}
// async global->LDS, 16B/lane; LDS dest = wave-uniform base + lane*16 (m97).
__device__ __forceinline__ void async_copy16(const u16* gsrc, u16* ldst) {
    __builtin_amdgcn_global_load_lds(
        (const __attribute__((address_space(1))) void*)gsrc,
        (__attribute__((address_space(3))) void*)ldst, 16, 0, 0);
}

// ---------------------------------------------------------------------------
// f32 -> bf16 pre-conversion.
// ---------------------------------------------------------------------------
__global__ void cvt_w_k(const float* __restrict__ Wq, const float* __restrict__ Wk,
                        const float* __restrict__ Wv, const float* __restrict__ Wo,
                        u16* __restrict__ Wqkv, u16* __restrict__ Wob)
{
    int g = blockIdx.x * 256 + threadIdx.x;   // granule id, 0..524287
    int w = g >> 17;                          // 0..3 (whole blocks uniform)
    int off = g & 131071;
    const float* src = (w == 0) ? Wq : (w == 1) ? Wk : (w == 2) ? Wv : Wo;
    u16* dst = (w < 3) ? (Wqkv + ((size_t)w << 20)) : Wob;
    *(bf16x8*)&dst[(size_t)off * 8] = cvt8(src + (size_t)off * 8);
}

__global__ void cvt_x_k(const float* __restrict__ xs, u16* __restrict__ xb)
{
    size_t g = (size_t)blockIdx.x * 256 + threadIdx.x;
    *(bf16x8*)&xb[g * 8] = cvt8(xs + g * 8);
}

// ---------------------------------------------------------------------------
// Fused QKV GEMM (round-4 best-measured form: 109 us, 456 TF).
// 128x128 tile, BK=64, 4 waves, 1-phase staging (inter-block TLP at >=3
// blocks/CU does the latency hiding -- explicit dbuf measured WORSE, r7).
// XCD-chunked mapping; LDS-restaged head-plane epilogue (ideal WRITE_SIZE).
// launch_bounds min-waves raised 2->4: VGPR=64 + 32KB LDS allow up to
// 5 blocks/CU; observed ceiling was 3 -- request more.
// ---------------------------------------------------------------------------
__global__ __launch_bounds__(256, 4) void qkv_gemm_k(
    const u16* __restrict__ xb, const u16* __restrict__ Wqkv,
    const float* __restrict__ bq, const float* __restrict__ bk,
    const float* __restrict__ bv,
    u16* __restrict__ Qh, u16* __restrict__ Kh, u16* __restrict__ Vh,
    int mblocks)
{
    __shared__ __align__(16) u16 sh[2][128 * 64];
    u16* aSh = sh[0];
    u16* bSh = sh[1];
    int t = threadIdx.x, lane = t & 63, w = t >> 6;
    int q = lane >> 4, ln = lane & 15;
    int wm = (w & 1) * 64, wn = (w >> 1) * 64;
    int bid = blockIdx.x;
    int xcd = bid & 7, local = bid >> 3;
    int mPerX = mblocks >> 3;                 // mblocks % 8 == 0
    int ml = local % mPerX, nn = local / mPerX;
    int m0 = (xcd * mPerX + ml) * 128, n0 = nn * 128;
    int wgr = t & 192;
    floatx4 acc[4][4] = {};

    for (int k0 = 0; k0 < DM; k0 += 64) {
#pragma unroll
        for (int i = 0; i < 4; ++i) {
            int gi = i * 256 + t;
            int r = gi >> 3;
            int c = (gi & 7) ^ (r & 7);
            async_copy16(xb + (size_t)(m0 + r) * DM + k0 + c * 8,
                         aSh + (size_t)(i * 256 + wgr) * 8);
            async_copy16(Wqkv + (size_t)(n0 + r) * DM + k0 + c * 8,
                         bSh + (size_t)(i * 256 + wgr) * 8);
        }
        __builtin_amdgcn_s_waitcnt(0);
        __syncthreads();
#pragma unroll
        for (int ks = 0; ks < 2; ++ks) {
            int cg = ks * 4 + q;
            bf16x8 af[4], bfv[4];
#pragma unroll
            for (int tm = 0; tm < 4; ++tm) {
                int m = wm + tm * 16 + ln;
                af[tm] = *(const bf16x8*)&aSh[(m * 8 + (cg ^ (m & 7))) * 8];
            }
#pragma unroll
            for (int tn = 0; tn < 4; ++tn) {
                int n = wn + tn * 16 + ln;
                bfv[tn] = *(const bf16x8*)&bSh[(n * 8 + (cg ^ (n & 7))) * 8];
            }
#pragma unroll
            for (int tm = 0; tm < 4; ++tm)
#pragma unroll
                for (int tn = 0; tn < 4; ++tn)
                    acc[tm][tn] = __builtin_amdgcn_mfma_f32_16x16x32_bf16(
                        af[tm], bfv[tn], acc[tm][tn], 0, 0, 0);
        }
        __syncthreads();
    }
    // Epilogue: bias+phi, stage C tile in LDS (granule-XOR vs row to spread
    // banks), then 2 heads x 16KB contiguous coalesced stores.
    int proj = n0 >> 10, colb = n0 & 1023;
    const float* bias = (proj == 0) ? bq : (proj == 1) ? bk : bv;
    u16* plane = (proj == 0) ? Qh : (proj == 1) ? Kh : Vh;
    u16* cSh = sh[0];                          // 32 KB = 128x128 u16
#pragma unroll
    for (int tn = 0; tn < 4; ++tn) {
        int lc = wn + tn * 16 + ln;
        float bb = bias[colb + lc];
        int gr = lc >> 3, lo = lc & 7;
#pragma unroll
        for (int tm = 0; tm < 4; ++tm) {
            int lrb = wm + tm * 16 + q * 4;
#pragma unroll
            for (int r = 0; r < 4; ++r) {
                int lr = lrb + r;
                float v = acc[tm][tn][r] + bb;
                if (proj < 2) v = (v > 0.f) ? (v + 1.f) : __expf(v);
                cSh[lr * 128 + ((gr & 8) | ((gr ^ lr) & 7)) * 8 + lo] = f2bf(v);
            }
        }
    }
    __syncthreads();
    int head0 = colb >> 6;
    size_t blk = (size_t)(m0 >> 12);
    int mrow = m0 & 4095;
#pragma unroll
    for (int h = 0; h < 2; ++h) {
        u16* pb = plane + ((blk * NH + head0 + h) * SEQ + mrow) * HD;
#pragma unroll
        for (int it = 0; it < 4; ++it) {
            int gi = it * 256 + t;             // 16B chunk id, 0..1023
            int s = gi >> 3, g = gi & 7;
            *(bf16x8*)&pb[(size_t)gi * 8] =
                *(const bf16x8*)&cSh[s * 128 + ((h * 8) | (g ^ (s & 7))) * 8];
        }
    }
}

// ---------------------------------------------------------------------------
// Output GEMM: A = head-major bf16 plane (attn out), Wob bf16, out f32.
// 2-phase double-buffered (kept from r7: the "rest" improved ~45us there;
// out_gemm's scattered head-major A-loads benefit from prefetch).
// ---------------------------------------------------------------------------
__global__ __launch_bounds__(256, 2) void out_gemm_k(
    const u16* __restrict__ Ah, const u16* __restrict__ Wob,
    const float* __restrict__ bo, float* __restrict__ out, int mblocks)
{
    __shared__ __align__(16) u16 lds[32768];
    int t = threadIdx.x, lane = t & 63, w = t >> 6;
    int q = lane >> 4, ln = lane & 15;
    int wm = (w & 1) * 64, wn = (w >> 1) * 64;
    int bid = blockIdx.x;
    int xcd = bid & 7, local = bid >> 3;
    int mPerX = mblocks >> 3;
    int ml = local % mPerX, nn = local / mPerX;
    int m0 = (xcd * mPerX + ml) * 128, n0 = nn * 128;
    int wgr = t & 192;
    floatx4 acc[4][4] = {};

    auto STAGE = [&](int kk, int buf) {
        int k0 = kk * 64;
        u16* aS = lds + buf * 16384;
        u16* bS = aS + 8192;
#pragma unroll
        for (int i = 0; i < 4; ++i) {
            int gi = i * 256 + t;
            int r = gi >> 3;
            int c = (gi & 7) ^ (r & 7);
            int rr = m0 + r;  // plane: ((bl*16+head)*4096+s)*64+dl ; head=k0>>6
            async_copy16(Ah + (((size_t)((rr >> 12) * NH + (k0 >> 6))) << 18)
                            + (size_t)((rr & 4095) << 6) + (size_t)(c * 8),
                         aS + (size_t)(i * 256 + wgr) * 8);
            async_copy16(Wob + (size_t)(n0 + r) * DM + k0 + c * 8,
                         bS + (size_t)(i * 256 + wgr) * 8);
        }
    };

    STAGE(0, 0);
    __syncthreads();
    for (int tt = 0; tt < 16; ++tt) {
        int p = tt & 1;
        if (tt < 15) STAGE(tt + 1, p ^ 1);
        const u16* aS = lds + p * 16384;
        const u16* bS = aS + 8192;
#pragma unroll
        for (int ks = 0; ks < 2; ++ks) {
            int cg = ks * 4 + q;
            bf16x8 af[4], bfv[4];
#pragma unroll
            for (int tm = 0; tm < 4; ++tm) {
                int m = wm + tm * 16 + ln;
                af[tm] = *(const bf16x8*)&aS[(m * 8 + (cg ^ (m & 7))) * 8];
            }
#pragma unroll
            for (int tn = 0; tn < 4; ++tn) {
                int n = wn + tn * 16 + ln;
                bfv[tn] = *(const bf16x8*)&bS[(n * 8 + (cg ^ (n & 7))) * 8];
            }
#pragma unroll
            for (int tm = 0; tm < 4; ++tm)
#pragma unroll
                for (int tn = 0; tn < 4; ++tn)
                    acc[tm][tn] = __builtin_amdgcn_mfma_f32_16x16x32_bf16(
                        af[tm], bfv[tn], acc[tm][tn], 0, 0, 0);
        }
        __syncthreads();
    }
#pragma unroll
    for (int tn = 0; tn < 4; ++tn) {
        int gn = n0 + wn + tn * 16 + ln;
        float bb = bo[gn];
#pragma unroll
        for (int tm = 0; tm < 4; ++tm) {
            int gmb = m0 + wm + tm * 16 + q * 4;
#pragma unroll
            for (int r = 0; r < 4; ++r)
                out[(size_t)(gmb + r) * DM + gn] = acc[tm][tn][r] + bb;
        }
    }
}

// ---------------------------------------------------------------------------
// Per (head,chunk): St[e][d] = sum_r V[r][e]*K[r][d]  (S TRANSPOSED, bf16);
// Zc[d] = sum_r K[r][d].  S^T layout makes attn's Q@S B-frags vector loads.
// ---------------------------------------------------------------------------
__global__ __launch_bounds__(256, 1) void chunk_stats_k(
    const u16* __restrict__ Kh, const u16* __restrict__ Vh,
    u16* __restrict__ Sc, float* __restrict__ Zc)
{
    __shared__ __align__(16) u16 kSh[128 * 64];
    __shared__ __align__(16) u16 vSh[128 * 64];
    __shared__ float zpart[4][64];
    int t = threadIdx.x;
    int bhc = blockIdx.x;
    const u16* Kb = Kh + ((size_t)(bhc >> 5) * SEQ + (size_t)(bhc & 31) * CHUNK) * HD;
    const u16* Vb = Vh + ((size_t)(bhc >> 5) * SEQ + (size_t)(bhc & 31) * CHUNK) * HD;
#pragma unroll
    for (int i = 0; i < 4; ++i) {
        int g = i * 256 + t;
        *(bf16x8*)&kSh[g * 8] = *(const bf16x8*)&Kb[(size_t)g * 8];
        *(bf16x8*)&vSh[g * 8] = *(const bf16x8*)&Vb[(size_t)g * 8];
    }
    __syncthreads();
    int tD = t & 15, tE = t >> 4;   // d-group, e-group
    float acc[4][4] = {};
#pragma unroll 8
    for (int r = 0; r < 128; ++r) {
        bf16x4 vq = *(const bf16x4*)&vSh[r * 64 + tE * 4];
        bf16x4 kq = *(const bf16x4*)&kSh[r * 64 + tD * 4];
        float vf[4], kf[4];
#pragma unroll
        for (int i = 0; i < 4; ++i) { vf[i] = bf2f((u16)vq[i]); kf[i] = bf2f((u16)kq[i]); }
#pragma unroll
        for (int a = 0; a < 4; ++a)
#pragma unroll
            for (int b = 0; b < 4; ++b) acc[a][b] += vf[a] * kf[b];
    }
    u16* So = Sc + (size_t)bhc * HD * HD;
#pragma unroll
    for (int a = 0; a < 4; ++a) {
        bf16x4 sv;
#pragma unroll
        for (int b = 0; b < 4; ++b) sv[b] = (short)f2bf(acc[a][b]);
        *(bf16x4*)&So[(tE * 4 + a) * HD + tD * 4] = sv;  // S^T: e row, d cols
    }
    // Z: all 256 threads sum 32 rows each for one d column, then combine.
    {
        int dz = t & 63, qz = t >> 6;
        float z = 0.f;
#pragma unroll
        for (int r = 0; r < 32; ++r) z += bf2f(kSh[(qz * 32 + r) * 64 + dz]);
        zpart[qz][dz] = z;
    }
    __syncthreads();
    if (t < 64)
        Zc[(size_t)bhc * HD + t] =
            zpart[0][t] + zpart[1][t] + zpart[2][t] + zpart[3][t];
}

// ---------------------------------------------------------------------------
// Exclusive prefix over 32 chunks (per bh). Elementwise -> layout-agnostic.
// Loads batched into registers first (no load->store->load serial chain).
// ---------------------------------------------------------------------------
__global__ void prefix_k(u16* __restrict__ Sc, float* __restrict__ Zc)
{
    int bh = blockIdx.x, y = blockIdx.y, t = threadIdx.x;
    if (y < 32) {
        size_t base = (size_t)bh * 32 * 4096 + y * 128 + t;
        u16 vals[32];
#pragma unroll
        for (int c = 0; c < 32; ++c) vals[c] = Sc[base + (size_t)c * 4096];
        float run = 0.f;
#pragma unroll
        for (int c = 0; c < 32; ++c) {
            float cur = bf2f(vals[c]);
            Sc[base + (size_t)c * 4096] = f2bf(run);
            run += cur;
        }
    } else if (t < 64) {
        size_t base = (size_t)bh * 32 * 64 + t;
        float zv[32];
#pragma unroll
        for (int c = 0; c < 32; ++c) zv[c] = Zc[base + (size_t)c * 64];
        float run = 0.f;
#pragma unroll
        for (int c = 0; c < 32; ++c) {
            Zc[base + (size_t)c * 64] = run;
            run += zv[c];
        }
    }
}

// ---------------------------------------------------------------------------
// Per (head,chunk): P = tril(Q K^T); den = rowsum(P)+Q.z_pre;
// num = P@V + Q@S_pre^T; out = num/den written IN PLACE over the Q plane.
// ---------------------------------------------------------------------------
__global__ __launch_bounds__(256, 1) void attn_out_k(
    const u16* Qh, const u16* __restrict__ Kh,
    const u16* __restrict__ Vh, const u16* __restrict__ Sp,
    const float* __restrict__ Zp, u16* Qw)
{
    __shared__ __align__(16) u16 vtSh[64 * 136];   // V^T, +8 pad
    __shared__ __align__(16) u16 pSh[128 * 136];   // P; reused as out staging
    __shared__ float psum[128];
    __shared__ float qzs[128];
    int t = threadIdx.x, lane = t & 63, w = t >> 6;
    int q = lane >> 4, ln = lane & 15;
    int bhc = blockIdx.x, bh = bhc >> 5, ch = bhc & 31;
    const u16* Qb = Qh + ((size_t)bh * SEQ + (size_t)ch * CHUNK) * HD;
    const u16* Kb = Kh + ((size_t)bh * SEQ + (size_t)ch * CHUNK) * HD;
    const u16* Vb = Vh + ((size_t)bh * SEQ + (size_t)ch * CHUNK) * HD;
    const u16* Spb = Sp + (size_t)bhc * HD * HD;   // S^T[e][d]
    const float* Zpb = Zp + (size_t)bhc * HD;

    // stage V^T
#pragma unroll
    for (int i = 0; i < 4; ++i) {
        int g = i * 256 + t;
        int k = g >> 3, e0 = (g & 7) * 8;
        bf16x8 vv = *(const bf16x8*)&Vb[(size_t)k * HD + e0];
#pragma unroll
        for (int j = 0; j < 8; ++j) vtSh[(e0 + j) * 136 + k] = (u16)vv[j];
    }

    // GEMM1: scores = Q K^T, fragments straight from global
    int wm = (w & 1) * 64, wn = (w >> 1) * 64;
    bf16x8 afr[2][4];  // kept for Q@S_pre later
#pragma unroll
    for (int ks = 0; ks < 2; ++ks)
#pragma unroll
        for (int tm = 0; tm < 4; ++tm) {
            int m = wm + tm * 16 + ln;
            afr[ks][tm] = *(const bf16x8*)&Qb[(size_t)m * HD + ks * 32 + q * 8];
        }
    floatx4 acc[4][4] = {};
#pragma unroll
    for (int ks = 0; ks < 2; ++ks) {
        bf16x8 bfr[4];
#pragma unroll
        for (int tn = 0; tn < 4; ++tn) {
            int n = wn + tn * 16 + ln;
            bfr[tn] = *(const bf16x8*)&Kb[(size_t)n * HD + ks * 32 + q * 8];
        }
#pragma unroll
        for (int tm = 0; tm < 4; ++tm)
#pragma unroll
            for (int tn = 0; tn < 4; ++tn)
                acc[tm][tn] = __builtin_amdgcn_mfma_f32_16x16x32_bf16(
                    afr[ks][tm], bfr[tn], acc[tm][tn], 0, 0, 0);
    }
    // mask + write P
#pragma unroll
    for (int tm = 0; tm < 4; ++tm) {
        int rb = wm + tm * 16 + q * 4;
#pragma unroll
        for (int tn = 0; tn < 4; ++tn) {
            int cc = wn + tn * 16 + ln;
#pragma unroll
            for (int r = 0; r < 4; ++r) {
                float v = (cc <= rb + r) ? acc[tm][tn][r] : 0.f;
                pSh[(rb + r) * 136 + cc] = f2bf(v);
            }
        }
    }
    __syncthreads();
    // den parts
    if (t < 128) {
        const u16* prow = &pSh[t * 136];
        float s = 0.f;
#pragma unroll
        for (int i = 0; i < 16; ++i) {
            bf16x8 pv = *(const bf16x8*)&prow[i * 8];
#pragma unroll
            for (int j = 0; j < 8; ++j) s += bf2f((u16)pv[j]);
        }
        psum[t] = s;
    } else {
        int row = t - 128;
        float s = 0.f;
#pragma unroll
        for (int i = 0; i < 8; ++i) {
            bf16x8 qv = *(const bf16x8*)&Qb[(size_t)row * HD + i * 8];
#pragma unroll
            for (int j = 0; j < 8; ++j) s += bf2f((u16)qv[j]) * Zpb[i * 8 + j];
        }
        qzs[row] = s;
    }
    __syncthreads();

    // GEMM2: num = P @ V (K=128) + Q @ S_pre (K=64, S^T rows = vector loads)
    int wn2 = (w >> 1) * 32;
    floatx4 acc2[4][2] = {};
#pragma unroll
    for (int ks = 0; ks < 4; ++ks) {
        bf16x8 ap[4], bv[2];
#pragma unroll
        for (int tm = 0; tm < 4; ++tm) {
            int m = wm + tm * 16 + ln;
            ap[tm] = *(const bf16x8*)&pSh[m * 136 + ks * 32 + q * 8];
        }
#pragma unroll
        for (int tn = 0; tn < 2; ++tn) {
            int n = wn2 + tn * 16 + ln;
            bv[tn] = *(const bf16x8*)&vtSh[n * 136 + ks * 32 + q * 8];
        }
#pragma unroll
        for (int tm = 0; tm < 4; ++tm)
#pragma unroll
            for (int tn = 0; tn < 2; ++tn)
                acc2[tm][tn] = __builtin_amdgcn_mfma_f32_16x16x32_bf16(
                    ap[tm], bv[tn], acc2[tm][tn], 0, 0, 0);
    }
#pragma unroll
    for (int ks = 0; ks < 2; ++ks) {
        bf16x8 bs[2];
#pragma unroll
        for (int tn = 0; tn < 2; ++tn) {
            int n = wn2 + tn * 16 + ln;        // e
            bs[tn] = *(const bf16x8*)&Spb[(size_t)n * HD + ks * 32 + q * 8];
        }
#pragma unroll
        for (int tm = 0; tm < 4; ++tm)
#pragma unroll
            for (int tn = 0; tn < 2; ++tn)
                acc2[tm][tn] = __builtin_amdgcn_mfma_f32_16x16x32_bf16(
                    afr[ks][tm], bs[tn], acc2[tm][tn], 0, 0, 0);
    }
    // epilogue: divide, re-stage via LDS (stride 72 u16, 16B-aligned rows),
    // then fully-coalesced 16B stores into the contiguous 16KB out region.
    __syncthreads();   // GEMM2 pSh reads complete before overwrite
#pragma unroll
    for (int tm = 0; tm < 4; ++tm) {
        int rb = wm + tm * 16 + q * 4;
#pragma unroll
        for (int r = 0; r < 4; ++r) {
            int mrow = rb + r;
            float inv = 1.0f / fmaxf(psum[mrow] + qzs[mrow], 1e-20f);
#pragma unroll
            for (int tn = 0; tn < 2; ++tn) {
                int e = wn2 + tn * 16 + ln;
                pSh[mrow * 72 + e] = f2bf(acc2[tm][tn][r] * inv);
            }
        }
    }
    __syncthreads();
    size_t obase = ((size_t)bh * SEQ + (size_t)ch * CHUNK) * HD;
#pragma unroll
    for (int j = 0; j < 4; ++j) {
        int ci = j * 256 + t;                 // 16B chunk index, 0..1023
        *(bf16x8*)&Qw[obase + (size_t)ci * 8] =
            *(const bf16x8*)&pSh[(ci >> 3) * 72 + (ci & 7) * 8];
    }
}

extern "C" void kernel_launch(void* const* d_in, const int* in_sizes, int n_in,
                              void* d_out, int out_size, void* d_ws, size_t ws_size,
                              hipStream_t stream) {
    const float* x  = (const float*)d_in[0];
    const float* Wq = (const float*)d_in[1];
    const float* bq = (const float*)d_in[2];
    const float* Wk = (const float*)d_in[3];
    const float* bk = (const float*)d_in[4];
    const float* Wv = (const float*)d_in[5];
    const float* bv = (const float*)d_in[6];
    const float* Wo = (const float*)d_in[7];
    const float* bo = (const float*)d_in[8];
    float* out = (float*)d_out;

    const size_t PLANE = (size_t)NH * SEQ * HD;
    const size_t FIXED = (3 * (size_t)DM * DM + (size_t)DM * DM) * 2;
    const size_t PER_BATCH = 4 * PLANE * 2 + (size_t)NH * 32 * 4096 * 2
                           + (size_t)NH * 32 * HD * 4;
    if (ws_size < FIXED + PER_BATCH) return;
    int nb = (ws_size >= FIXED + 4 * PER_BATCH) ? 4
           : (ws_size >= FIXED + 2 * PER_BATCH) ? 2 : 1;

    char* p0 = (char*)d_ws;
    u16* Wqkv = (u16*)p0;                       p0 += 3 * (size_t)DM * DM * 2;
    u16* Wob  = (u16*)p0;                       p0 += (size_t)DM * DM * 2;

    cvt_w_k<<<dim3(2048), dim3(256), 0, stream>>>(Wq, Wk, Wv, Wo, Wqkv, Wob);

    for (int b0 = 0; b0 < 4; b0 += nb) {
        char* p = p0;
        u16* xb = (u16*)p;  p += (size_t)nb * PLANE * 2;
        u16* Qh = (u16*)p;  p += (size_t)nb * PLANE * 2;
        u16* Kh = (u16*)p;  p += (size_t)nb * PLANE * 2;
        u16* Vh = (u16*)p;  p += (size_t)nb * PLANE * 2;
        u16* Sc = (u16*)p;  p += (size_t)nb * NH * 32 * 4096 * 2;
        float* Zc = (float*)p;
        const float* xs = x + (size_t)b0 * SEQ * DM;
        int mb128 = nb * 32;   // 128-row m-blocks

        cvt_x_k<<<dim3(nb * 2048), dim3(256), 0, stream>>>(xs, xb);
        qkv_gemm_k<<<dim3(24 * mb128), dim3(256), 0, stream>>>(
            xb, Wqkv, bq, bk, bv, Qh, Kh, Vh, mb128);
        chunk_stats_k<<<dim3(nb * 512), dim3(256), 0, stream>>>(Kh, Vh, Sc, Zc);
        prefix_k<<<dim3(nb * 16, 33), dim3(128), 0, stream>>>(Sc, Zc);
        attn_out_k<<<dim3(nb * 512), dim3(256), 0, stream>>>(Qh, Kh, Vh, Sc, Zc, Qh);
        out_gemm_k<<<dim3(8 * mb128), dim3(256), 0, stream>>>(
            Qh, Wob, bo, out + (size_t)b0 * SEQ * DM, mb128);
    }
}

// Round 9
// 359.880 us; speedup vs baseline: 1.0576x; 1.0576x over previous
//
#include <hip/hip_runtime.h>
#include <hip/hip_bf16.h>

typedef __attribute__((ext_vector_type(8))) short bf16x8;
typedef __attribute__((ext_vector_type(4))) short bf16x4;
typedef __attribute__((ext_vector_type(4))) float floatx4;
typedef unsigned short u16;
typedef unsigned int u32;

#define DM 1024
#define SEQ 4096
#define NH 16
#define HD 64
#define CHUNK 128

__device__ __forceinline__ float bf2f(u16 x) {
    u32 u = ((u32)x) << 16;
    return __builtin_bit_cast(float, u);
}
__device__ __forceinline__ u16 f2bf(float f) {
    u32 u = __builtin_bit_cast(u32, f);
    u32 r = u + 0x7FFF + ((u >> 16) & 1);
    return (u16)(r >> 16);
}
__device__ __forceinline__ bf16x8 cvt8(const float* p) {
    floatx4 a = *(const floatx4*)p;
    floatx4 b = *(const floatx4*)(p + 4);
    bf16x8 r;
    r[0] = (short)f2bf(a[0]); r[1] = (short)f2bf(a[1]);
    r[2] = (short)f2bf(a[2]); r[3] = (short)f2bf(a[3]);
    r[4] = (short)f2bf(b[0]); r[5] = (short)f2bf(b[1]);
    r[6] = (short)f2bf(b[2]); r[7] = (short)f2bf(b[3]);
    return r;
}
// async global->LDS, 16B/lane; LDS dest = wave-uniform base + lane*16 (m97).
__device__ __forceinline__ void async_copy16(const u16* gsrc, u16* ldst) {
    __builtin_amdgcn_global_load_lds(
        (const __attribute__((address_space(1))) void*)gsrc,
        (__attribute__((address_space(3))) void*)ldst, 16, 0, 0);
}

// ---------------------------------------------------------------------------
// f32 -> bf16 pre-conversion.
// ---------------------------------------------------------------------------
__global__ void cvt_w_k(const float* __restrict__ Wq, const float* __restrict__ Wk,
                        const float* __restrict__ Wv, const float* __restrict__ Wo,
                        u16* __restrict__ Wqkv, u16* __restrict__ Wob)
{
    int g = blockIdx.x * 256 + threadIdx.x;   // granule id, 0..524287
    int w = g >> 17;                          // 0..3 (whole blocks uniform)
    int off = g & 131071;
    const float* src = (w == 0) ? Wq : (w == 1) ? Wk : (w == 2) ? Wv : Wo;
    u16* dst = (w < 3) ? (Wqkv + ((size_t)w << 20)) : Wob;
    *(bf16x8*)&dst[(size_t)off * 8] = cvt8(src + (size_t)off * 8);
}

__global__ void cvt_x_k(const float* __restrict__ xs, u16* __restrict__ xb)
{
    size_t g = (size_t)blockIdx.x * 256 + threadIdx.x;
    *(bf16x8*)&xb[g * 8] = cvt8(xs + g * 8);
}

// ---------------------------------------------------------------------------
// Fused QKV GEMM (937 TF measured = m97-structure ceiling; structure frozen).
// 128x128 tile, BK=64, 4 waves, 1-phase staging, XCD-chunked mapping.
// Epilogue: Q,K planes head-major [bh][s][d] (phi applied); V plane written
// CHUNK-TRANSPOSED [bh][ch][e(64)][k(128)] so chunk_stats gets direct MFMA
// A-frags and attn_out gets direct PV B-frags (no vtSh staging downstream).
// ---------------------------------------------------------------------------
__global__ __launch_bounds__(256, 2) void qkv_gemm_k(
    const u16* __restrict__ xb, const u16* __restrict__ Wqkv,
    const float* __restrict__ bq, const float* __restrict__ bk,
    const float* __restrict__ bv,
    u16* __restrict__ Qh, u16* __restrict__ Kh, u16* __restrict__ Vh,
    int mblocks)
{
    __shared__ __align__(16) u16 sh[2][128 * 64];
    u16* aSh = sh[0];
    u16* bSh = sh[1];
    int t = threadIdx.x, lane = t & 63, w = t >> 6;
    int q = lane >> 4, ln = lane & 15;
    int wm = (w & 1) * 64, wn = (w >> 1) * 64;
    int bid = blockIdx.x;
    int xcd = bid & 7, local = bid >> 3;
    int mPerX = mblocks >> 3;                 // mblocks % 8 == 0
    int ml = local % mPerX, nn = local / mPerX;
    int m0 = (xcd * mPerX + ml) * 128, n0 = nn * 128;
    int wgr = t & 192;
    floatx4 acc[4][4] = {};

    for (int k0 = 0; k0 < DM; k0 += 64) {
#pragma unroll
        for (int i = 0; i < 4; ++i) {
            int gi = i * 256 + t;
            int r = gi >> 3;
            int c = (gi & 7) ^ (r & 7);
            async_copy16(xb + (size_t)(m0 + r) * DM + k0 + c * 8,
                         aSh + (size_t)(i * 256 + wgr) * 8);
            async_copy16(Wqkv + (size_t)(n0 + r) * DM + k0 + c * 8,
                         bSh + (size_t)(i * 256 + wgr) * 8);
        }
        __builtin_amdgcn_s_waitcnt(0);
        __syncthreads();
#pragma unroll
        for (int ks = 0; ks < 2; ++ks) {
            int cg = ks * 4 + q;
            bf16x8 af[4], bfv[4];
#pragma unroll
            for (int tm = 0; tm < 4; ++tm) {
                int m = wm + tm * 16 + ln;
                af[tm] = *(const bf16x8*)&aSh[(m * 8 + (cg ^ (m & 7))) * 8];
            }
#pragma unroll
            for (int tn = 0; tn < 4; ++tn) {
                int n = wn + tn * 16 + ln;
                bfv[tn] = *(const bf16x8*)&bSh[(n * 8 + (cg ^ (n & 7))) * 8];
            }
#pragma unroll
            for (int tm = 0; tm < 4; ++tm)
#pragma unroll
                for (int tn = 0; tn < 4; ++tn)
                    acc[tm][tn] = __builtin_amdgcn_mfma_f32_16x16x32_bf16(
                        af[tm], bfv[tn], acc[tm][tn], 0, 0, 0);
        }
        __syncthreads();
    }
    int proj = n0 >> 10, colb = n0 & 1023;
    const float* bias = (proj == 0) ? bq : (proj == 1) ? bk : bv;
    u16* cSh = sh[0];                          // 32 KB = 16384 u16
    int head0 = colb >> 6;
    size_t blk = (size_t)(m0 >> 12);
    int mrow = m0 & 4095;
    if (proj < 2) {
        // Q,K: phi + row-major restage -> head-major [bh][s][d] planes.
        u16* plane = (proj == 0) ? Qh : Kh;
#pragma unroll
        for (int tn = 0; tn < 4; ++tn) {
            int lc = wn + tn * 16 + ln;
            float bb = bias[colb + lc];
            int gr = lc >> 3, lo = lc & 7;
#pragma unroll
            for (int tm = 0; tm < 4; ++tm) {
                int lrb = wm + tm * 16 + q * 4;
#pragma unroll
                for (int r = 0; r < 4; ++r) {
                    int lr = lrb + r;
                    float v = acc[tm][tn][r] + bb;
                    v = (v > 0.f) ? (v + 1.f) : __expf(v);
                    cSh[lr * 128 + ((gr & 8) | ((gr ^ lr) & 7)) * 8 + lo] = f2bf(v);
                }
            }
        }
        __syncthreads();
#pragma unroll
        for (int h = 0; h < 2; ++h) {
            u16* pb = plane + ((blk * NH + head0 + h) * SEQ + mrow) * HD;
#pragma unroll
            for (int it = 0; it < 4; ++it) {
                int gi = it * 256 + t;             // 16B chunk id, 0..1023
                int s = gi >> 3, g = gi & 7;
                *(bf16x8*)&pb[(size_t)gi * 8] =
                    *(const bf16x8*)&cSh[s * 128 + ((h * 8) | (g ^ (s & 7))) * 8];
            }
        }
    } else {
        // V: transposed restage; m-tile == one chunk (128 rows).  cSh layout
        // [lc(128)][lr(128)] with granule-XOR: addr = lc*128 + ((lr>>3)^(lc&7))*8
        // + (lr&7).  Write scalar (as before), read vectorized.
        int chk = mrow >> 7;
#pragma unroll
        for (int tn = 0; tn < 4; ++tn) {
            int lc = wn + tn * 16 + ln;
            float bb = bias[colb + lc];
#pragma unroll
            for (int tm = 0; tm < 4; ++tm) {
                int lrb = wm + tm * 16 + q * 4;
#pragma unroll
                for (int r = 0; r < 4; ++r) {
                    int lr = lrb + r;
                    float v = acc[tm][tn][r] + bb;
                    cSh[lc * 128 + (((lr >> 3) ^ (lc & 7)) * 8) + (lr & 7)]
                        = f2bf(v);
                }
            }
        }
        __syncthreads();
#pragma unroll
        for (int h = 0; h < 2; ++h) {
            // Vt plane: [bh][ch][e(64)][k(128)], 8192 u16 per (bh,ch)
            u16* pb = Vh + (((blk * NH + head0 + h) * 32 + chk) << 13);
#pragma unroll
            for (int it = 0; it < 4; ++it) {
                int ci = it * 256 + t;             // 0..1023: e=ci>>4, g=ci&15
                int lc = h * 64 + (ci >> 4);
                int g = ci & 15;
                *(bf16x8*)&pb[(size_t)ci * 8] =
                    *(const bf16x8*)&cSh[lc * 128 + ((g ^ (lc & 7)) * 8)];
            }
        }
    }
}

// ---------------------------------------------------------------------------
// Output GEMM: A = head-major bf16 plane (attn out), Wob bf16, out f32.
// 2-phase double-buffered; XCD-chunked mapping.
// ---------------------------------------------------------------------------
__global__ __launch_bounds__(256, 2) void out_gemm_k(
    const u16* __restrict__ Ah, const u16* __restrict__ Wob,
    const float* __restrict__ bo, float* __restrict__ out, int mblocks)
{
    __shared__ __align__(16) u16 lds[32768];
    int t = threadIdx.x, lane = t & 63, w = t >> 6;
    int q = lane >> 4, ln = lane & 15;
    int wm = (w & 1) * 64, wn = (w >> 1) * 64;
    int bid = blockIdx.x;
    int xcd = bid & 7, local = bid >> 3;
    int mPerX = mblocks >> 3;
    int ml = local % mPerX, nn = local / mPerX;
    int m0 = (xcd * mPerX + ml) * 128, n0 = nn * 128;
    int wgr = t & 192;
    floatx4 acc[4][4] = {};

    auto STAGE = [&](int kk, int buf) {
        int k0 = kk * 64;
        u16* aS = lds + buf * 16384;
        u16* bS = aS + 8192;
#pragma unroll
        for (int i = 0; i < 4; ++i) {
            int gi = i * 256 + t;
            int r = gi >> 3;
            int c = (gi & 7) ^ (r & 7);
            int rr = m0 + r;  // plane: ((bl*16+head)*4096+s)*64+dl ; head=k0>>6
            async_copy16(Ah + (((size_t)((rr >> 12) * NH + (k0 >> 6))) << 18)
                            + (size_t)((rr & 4095) << 6) + (size_t)(c * 8),
                         aS + (size_t)(i * 256 + wgr) * 8);
            async_copy16(Wob + (size_t)(n0 + r) * DM + k0 + c * 8,
                         bS + (size_t)(i * 256 + wgr) * 8);
        }
    };

    STAGE(0, 0);
    __syncthreads();
    for (int tt = 0; tt < 16; ++tt) {
        int p = tt & 1;
        if (tt < 15) STAGE(tt + 1, p ^ 1);
        const u16* aS = lds + p * 16384;
        const u16* bS = aS + 8192;
#pragma unroll
        for (int ks = 0; ks < 2; ++ks) {
            int cg = ks * 4 + q;
            bf16x8 af[4], bfv[4];
#pragma unroll
            for (int tm = 0; tm < 4; ++tm) {
                int m = wm + tm * 16 + ln;
                af[tm] = *(const bf16x8*)&aS[(m * 8 + (cg ^ (m & 7))) * 8];
            }
#pragma unroll
            for (int tn = 0; tn < 4; ++tn) {
                int n = wn + tn * 16 + ln;
                bfv[tn] = *(const bf16x8*)&bS[(n * 8 + (cg ^ (n & 7))) * 8];
            }
#pragma unroll
            for (int tm = 0; tm < 4; ++tm)
#pragma unroll
                for (int tn = 0; tn < 4; ++tn)
                    acc[tm][tn] = __builtin_amdgcn_mfma_f32_16x16x32_bf16(
                        af[tm], bfv[tn], acc[tm][tn], 0, 0, 0);
        }
        __syncthreads();
    }
#pragma unroll
    for (int tn = 0; tn < 4; ++tn) {
        int gn = n0 + wn + tn * 16 + ln;
        float bb = bo[gn];
#pragma unroll
        for (int tm = 0; tm < 4; ++tm) {
            int gmb = m0 + wm + tm * 16 + q * 4;
#pragma unroll
            for (int r = 0; r < 4; ++r)
                out[(size_t)(gmb + r) * DM + gn] = acc[tm][tn][r] + bb;
        }
    }
}

// ---------------------------------------------------------------------------
// Per (head,chunk): St[e][d] = sum_r V[r][e]*K[r][d] via MFMA (was serial
// VALU outer-product, ~25us).  A-frags direct from transposed V plane;
// B-frags from LDS-staged K^T (pad-130 stride).  Zc[d] = sum_r K[r][d]
// from ktSh.  St stored bf16 S^T layout (same as before).
// ---------------------------------------------------------------------------
__global__ __launch_bounds__(256, 1) void chunk_stats_k(
    const u16* __restrict__ Kh, const u16* __restrict__ Vt,
    u16* __restrict__ Sc, float* __restrict__ Zc)
{
    __shared__ __align__(16) u16 ktSh[64 * 130];   // K^T [d][r], pad 130
    __shared__ float zpart[4][64];
    int t = threadIdx.x, lane = t & 63, w = t >> 6;
    int q = lane >> 4, ln = lane & 15;
    int bhc = blockIdx.x, bh = bhc >> 5, ch = bhc & 31;
    const u16* Kb = Kh + ((size_t)bh * SEQ + (size_t)ch * CHUNK) * HD;
    const u16* Vtb = Vt + ((size_t)bh * 32 + ch) * 8192;   // [e(64)][r(128)]

    // stage K^T: granule gi -> r=gi>>3, d0=(gi&7)*8; scatter 8 u16
#pragma unroll
    for (int i = 0; i < 4; ++i) {
        int gi = i * 256 + t;
        int r = gi >> 3, d0 = (gi & 7) * 8;
        bf16x8 kv = *(const bf16x8*)&Kb[(size_t)r * HD + d0];
#pragma unroll
        for (int j = 0; j < 8; ++j) ktSh[(d0 + j) * 130 + r] = (u16)kv[j];
    }
    __syncthreads();

    // Z: thread (dz,qz) sums 32 r at row dz of ktSh
    {
        int dz = t & 63, qz = t >> 6;
        float z = 0.f;
#pragma unroll
        for (int r = 0; r < 32; ++r) z += bf2f(ktSh[dz * 130 + qz * 32 + r]);
        zpart[qz][dz] = z;
    }

    // MFMA: D[e][d] = sum_r Vt[e][r] * Kt[d][r];  4 waves = 2x2 (e,d) halves
    int we = (w & 1) * 32, wd = (w >> 1) * 32;
    floatx4 acc[2][2] = {};
#pragma unroll
    for (int ks = 0; ks < 4; ++ks) {
        bf16x8 af[2], bf[2];
#pragma unroll
        for (int fm = 0; fm < 2; ++fm)
            af[fm] = *(const bf16x8*)&Vtb[(size_t)(we + fm * 16 + ln) * 128
                                          + ks * 32 + q * 8];
#pragma unroll
        for (int fn = 0; fn < 2; ++fn)
            bf[fn] = *(const bf16x8*)&ktSh[(wd + fn * 16 + ln) * 130
                                           + ks * 32 + q * 8];
#pragma unroll
        for (int fm = 0; fm < 2; ++fm)
#pragma unroll
            for (int fn = 0; fn < 2; ++fn)
                acc[fm][fn] = __builtin_amdgcn_mfma_f32_16x16x32_bf16(
                    af[fm], bf[fn], acc[fm][fn], 0, 0, 0);
    }
    u16* So = Sc + (size_t)bhc * HD * HD;
#pragma unroll
    for (int fm = 0; fm < 2; ++fm)
#pragma unroll
        for (int fn = 0; fn < 2; ++fn)
#pragma unroll
            for (int r = 0; r < 4; ++r)
                So[(we + fm * 16 + q * 4 + r) * HD + wd + fn * 16 + ln]
                    = f2bf(acc[fm][fn][r]);
    __syncthreads();
    if (t < 64)
        Zc[(size_t)bhc * HD + t] =
            zpart[0][t] + zpart[1][t] + zpart[2][t] + zpart[3][t];
}

// ---------------------------------------------------------------------------
// Exclusive prefix over 32 chunks (per bh). Elementwise -> layout-agnostic.
// ---------------------------------------------------------------------------
__global__ void prefix_k(u16* __restrict__ Sc, float* __restrict__ Zc)
{
    int bh = blockIdx.x, y = blockIdx.y, t = threadIdx.x;
    if (y < 32) {
        size_t base = (size_t)bh * 32 * 4096 + y * 128 + t;
        u16 vals[32];
#pragma unroll
        for (int c = 0; c < 32; ++c) vals[c] = Sc[base + (size_t)c * 4096];
        float run = 0.f;
#pragma unroll
        for (int c = 0; c < 32; ++c) {
            float cur = bf2f(vals[c]);
            Sc[base + (size_t)c * 4096] = f2bf(run);
            run += cur;
        }
    } else if (t < 64) {
        size_t base = (size_t)bh * 32 * 64 + t;
        float zv[32];
#pragma unroll
        for (int c = 0; c < 32; ++c) zv[c] = Zc[base + (size_t)c * 64];
        float run = 0.f;
#pragma unroll
        for (int c = 0; c < 32; ++c) {
            Zc[base + (size_t)c * 64] = run;
            run += zv[c];
        }
    }
}

// ---------------------------------------------------------------------------
// Per (head,chunk): P = tril(Q K^T); den = rowsum(P)+Q.z_pre;
// num = P@V + Q@S_pre^T; out = num/den written IN PLACE over the Q plane.
// PV B-frags now load DIRECTLY from the transposed V plane (no vtSh):
// LDS 53->35.8 KB -> 4 blocks/CU.
// ---------------------------------------------------------------------------
__global__ __launch_bounds__(256, 4) void attn_out_k(
    const u16* Qh, const u16* __restrict__ Kh,
    const u16* __restrict__ Vt, const u16* __restrict__ Sp,
    const float* __restrict__ Zp, u16* Qw)
{
    __shared__ __align__(16) u16 pSh[128 * 136];   // P; reused as out staging
    __shared__ float psum[128];
    __shared__ float qzs[128];
    int t = threadIdx.x, lane = t & 63, w = t >> 6;
    int q = lane >> 4, ln = lane & 15;
    int bhc = blockIdx.x, bh = bhc >> 5, ch = bhc & 31;
    const u16* Qb = Qh + ((size_t)bh * SEQ + (size_t)ch * CHUNK) * HD;
    const u16* Kb = Kh + ((size_t)bh * SEQ + (size_t)ch * CHUNK) * HD;
    const u16* Vtb = Vt + ((size_t)bh * 32 + ch) * 8192;   // [e(64)][k(128)]
    const u16* Spb = Sp + (size_t)bhc * HD * HD;   // S^T[e][d]
    const float* Zpb = Zp + (size_t)bhc * HD;

    // GEMM1: scores = Q K^T, fragments straight from global
    int wm = (w & 1) * 64, wn = (w >> 1) * 64;
    bf16x8 afr[2][4];  // kept for Q@S_pre later
#pragma unroll
    for (int ks = 0; ks < 2; ++ks)
#pragma unroll
        for (int tm = 0; tm < 4; ++tm) {
            int m = wm + tm * 16 + ln;
            afr[ks][tm] = *(const bf16x8*)&Qb[(size_t)m * HD + ks * 32 + q * 8];
        }
    floatx4 acc[4][4] = {};
#pragma unroll
    for (int ks = 0; ks < 2; ++ks) {
        bf16x8 bfr[4];
#pragma unroll
        for (int tn = 0; tn < 4; ++tn) {
            int n = wn + tn * 16 + ln;
            bfr[tn] = *(const bf16x8*)&Kb[(size_t)n * HD + ks * 32 + q * 8];
        }
#pragma unroll
        for (int tm = 0; tm < 4; ++tm)
#pragma unroll
            for (int tn = 0; tn < 4; ++tn)
                acc[tm][tn] = __builtin_amdgcn_mfma_f32_16x16x32_bf16(
                    afr[ks][tm], bfr[tn], acc[tm][tn], 0, 0, 0);
    }
    // mask + write P
#pragma unroll
    for (int tm = 0; tm < 4; ++tm) {
        int rb = wm + tm * 16 + q * 4;
#pragma unroll
        for (int tn = 0; tn < 4; ++tn) {
            int cc = wn + tn * 16 + ln;
#pragma unroll
            for (int r = 0; r < 4; ++r) {
                float v = (cc <= rb + r) ? acc[tm][tn][r] : 0.f;
                pSh[(rb + r) * 136 + cc] = f2bf(v);
            }
        }
    }
    __syncthreads();
    // den parts
    if (t < 128) {
        const u16* prow = &pSh[t * 136];
        float s = 0.f;
#pragma unroll
        for (int i = 0; i < 16; ++i) {
            bf16x8 pv = *(const bf16x8*)&prow[i * 8];
#pragma unroll
            for (int j = 0; j < 8; ++j) s += bf2f((u16)pv[j]);
        }
        psum[t] = s;
    } else {
        int row = t - 128;
        float s = 0.f;
#pragma unroll
        for (int i = 0; i < 8; ++i) {
            bf16x8 qv = *(const bf16x8*)&Qb[(size_t)row * HD + i * 8];
#pragma unroll
            for (int j = 0; j < 8; ++j) s += bf2f((u16)qv[j]) * Zpb[i * 8 + j];
        }
        qzs[row] = s;
    }
    __syncthreads();

    // GEMM2: num = P @ V (K=128, V^T-frags from global) + Q @ S_pre (K=64)
    int wn2 = (w >> 1) * 32;
    floatx4 acc2[4][2] = {};
#pragma unroll
    for (int ks = 0; ks < 4; ++ks) {
        bf16x8 ap[4], bv[2];
#pragma unroll
        for (int tm = 0; tm < 4; ++tm) {
            int m = wm + tm * 16 + ln;
            ap[tm] = *(const bf16x8*)&pSh[m * 136 + ks * 32 + q * 8];
        }
#pragma unroll
        for (int tn = 0; tn < 2; ++tn) {
            int n = wn2 + tn * 16 + ln;        // e
            bv[tn] = *(const bf16x8*)&Vtb[(size_t)n * 128 + ks * 32 + q * 8];
        }
#pragma unroll
        for (int tm = 0; tm < 4; ++tm)
#pragma unroll
            for (int tn = 0; tn < 2; ++tn)
                acc2[tm][tn] = __builtin_amdgcn_mfma_f32_16x16x32_bf16(
                    ap[tm], bv[tn], acc2[tm][tn], 0, 0, 0);
    }
#pragma unroll
    for (int ks = 0; ks < 2; ++ks) {
        bf16x8 bs[2];
#pragma unroll
        for (int tn = 0; tn < 2; ++tn) {
            int n = wn2 + tn * 16 + ln;        // e
            bs[tn] = *(const bf16x8*)&Spb[(size_t)n * HD + ks * 32 + q * 8];
        }
#pragma unroll
        for (int tm = 0; tm < 4; ++tm)
#pragma unroll
            for (int tn = 0; tn < 2; ++tn)
                acc2[tm][tn] = __builtin_amdgcn_mfma_f32_16x16x32_bf16(
                    afr[ks][tm], bs[tn], acc2[tm][tn], 0, 0, 0);
    }
    // epilogue: divide, re-stage via LDS (stride 72 u16, 16B-aligned rows),
    // then fully-coalesced 16B stores into the contiguous 16KB out region.
    __syncthreads();   // GEMM2 pSh reads complete before overwrite
#pragma unroll
    for (int tm = 0; tm < 4; ++tm) {
        int rb = wm + tm * 16 + q * 4;
#pragma unroll
        for (int r = 0; r < 4; ++r) {
            int mrow = rb + r;
            float inv = 1.0f / fmaxf(psum[mrow] + qzs[mrow], 1e-20f);
#pragma unroll
            for (int tn = 0; tn < 2; ++tn) {
                int e = wn2 + tn * 16 + ln;
                pSh[mrow * 72 + e] = f2bf(acc2[tm][tn][r] * inv);
            }
        }
    }
    __syncthreads();
    size_t obase = ((size_t)bh * SEQ + (size_t)ch * CHUNK) * HD;
#pragma unroll
    for (int j = 0; j < 4; ++j) {
        int ci = j * 256 + t;                 // 16B chunk index, 0..1023
        *(bf16x8*)&Qw[obase + (size_t)ci * 8] =
            *(const bf16x8*)&pSh[(ci >> 3) * 72 + (ci & 7) * 8];
    }
}

extern "C" void kernel_launch(void* const* d_in, const int* in_sizes, int n_in,
                              void* d_out, int out_size, void* d_ws, size_t ws_size,
                              hipStream_t stream) {
    const float* x  = (const float*)d_in[0];
    const float* Wq = (const float*)d_in[1];
    const float* bq = (const float*)d_in[2];
    const float* Wk = (const float*)d_in[3];
    const float* bk = (const float*)d_in[4];
    const float* Wv = (const float*)d_in[5];
    const float* bv = (const float*)d_in[6];
    const float* Wo = (const float*)d_in[7];
    const float* bo = (const float*)d_in[8];
    float* out = (float*)d_out;

    const size_t PLANE = (size_t)NH * SEQ * HD;
    const size_t FIXED = (3 * (size_t)DM * DM + (size_t)DM * DM) * 2;
    const size_t PER_BATCH = 4 * PLANE * 2 + (size_t)NH * 32 * 4096 * 2
                           + (size_t)NH * 32 * HD * 4;
    if (ws_size < FIXED + PER_BATCH) return;
    int nb = (ws_size >= FIXED + 4 * PER_BATCH) ? 4
           : (ws_size >= FIXED + 2 * PER_BATCH) ? 2 : 1;

    char* p0 = (char*)d_ws;
    u16* Wqkv = (u16*)p0;                       p0 += 3 * (size_t)DM * DM * 2;
    u16* Wob  = (u16*)p0;                       p0 += (size_t)DM * DM * 2;

    cvt_w_k<<<dim3(2048), dim3(256), 0, stream>>>(Wq, Wk, Wv, Wo, Wqkv, Wob);

    for (int b0 = 0; b0 < 4; b0 += nb) {
        char* p = p0;
        u16* xb = (u16*)p;  p += (size_t)nb * PLANE * 2;
        u16* Qh = (u16*)p;  p += (size_t)nb * PLANE * 2;
        u16* Kh = (u16*)p;  p += (size_t)nb * PLANE * 2;
        u16* Vh = (u16*)p;  p += (size_t)nb * PLANE * 2;
        u16* Sc = (u16*)p;  p += (size_t)nb * NH * 32 * 4096 * 2;
        float* Zc = (float*)p;
        const float* xs = x + (size_t)b0 * SEQ * DM;
        int mb128 = nb * 32;   // 128-row m-blocks

        cvt_x_k<<<dim3(nb * 2048), dim3(256), 0, stream>>>(xs, xb);
        qkv_gemm_k<<<dim3(24 * mb128), dim3(256), 0, stream>>>(
            xb, Wqkv, bq, bk, bv, Qh, Kh, Vh, mb128);
        chunk_stats_k<<<dim3(nb * 512), dim3(256), 0, stream>>>(Kh, Vh, Sc, Zc);
        prefix_k<<<dim3(nb * 16, 33), dim3(128), 0, stream>>>(Sc, Zc);
        attn_out_k<<<dim3(nb * 512), dim3(256), 0, stream>>>(Qh, Kh, Vh, Sc, Zc, Qh);
        out_gemm_k<<<dim3(8 * mb128), dim3(256), 0, stream>>>(
            Qh, Wob, bo, out + (size_t)b0 * SEQ * DM, mb128);
    }
}